// Round 17
// baseline (52.674 us; speedup 1.0000x reference)
//
#include <hip/hip_runtime.h>
#include <math.h>

// CasperNet R17: B=131072, D=256, H=64, O=10.
// vs R16 (50us, VALUBusy 25%, occ 40%, latency-bound):
//  1) transpose patch ALIASED into sW (dead after phase-1; one
//     __syncthreads at the boundary) -> LDS 61.9->51.5KB -> 3 blocks/CU
//     = 24 waves (75% nominal; VGPR 64 <= 85 so the VGPR limit allows it).
//  2) SCATTER-form solve: after h[k], push s[j] += U[j][k]*h[k] (j>k).
//     Same add order (k ascending) -> bit-identical to R16's gather;
//     serial chain/group 880 -> ~460 cy (sigm->1 fma->sigm).
//  3) staging writes as one short4 b64 (was 4x b16 with 4-way conflicts
//     = the constant 1280 conflict-cy/block seen since R9).
// Structure otherwise identical to R16 (verified): MFMA phase-1,
// blocked cascade = transpose + lane-local solve (s_load tri table)
// + rank-16 MFMA updates (B-frags prepped in d_ws).
// Layout (verified R5): MFMA C: col=lane&15, row=(lane>>4)*4+reg;
// A-frag: lane(lm,lg) = A[row=lm][k=lg*8+j].

#define DIMD 256
#define DIMH 64
#define DIMO 10
#define DT   320
#define NT   5        // 5 n-tiles of 16 = 80 cols (74 used)
#define TM   128      // rows per block: 8 waves x 16
#define BLOCK 512
#define UBOFF 2048    // byte offset of B-frag blob in d_ws (16B aligned)

typedef __attribute__((ext_vector_type(4))) float f32x4;
typedef __attribute__((ext_vector_type(8))) short bf16x8;

__device__ inline unsigned short f2bf(float f) {   // RNE, deterministic
    union { float f; unsigned u; } v; v.f = f;
    unsigned r = v.u + 0x7FFFu + ((v.u >> 16) & 1u);
    return (unsigned short)(r >> 16);
}
__device__ inline float sigm(float s) {
    return __builtin_amdgcn_rcpf(1.0f + __expf(-s));   // v_rcp_f32
}

// ---- prep: (a) 480-float tri table cfd[g][k(k-1)/2+m] = U diag blocks;
//            (b) 640 x u16x8 B-frag blob for the 10 (g,t) MFMA slots ----
__global__ void caspernet_prep(const float* __restrict__ Wh,
                               const float* __restrict__ Wo,
                               float* __restrict__ ws)
{
    const int tid = threadIdx.x;
    if (tid < 480) {
        const int g = tid / 120, r = tid % 120;
        int k = 1;
        while (k * (k + 1) / 2 <= r) ++k;          // k(k-1)/2 <= r < k(k+1)/2
        const int m = r - k * (k - 1) / 2;
        ws[tid] = Wh[(g * 16 + k) * DT + DIMD + (g * 16 + m)];
    }
    if (tid < 640) {
        const int p = tid >> 6, l = tid & 63;
        int g, t;
        if      (p < 4) { g = 0; t = p + 1; }
        else if (p < 7) { g = 1; t = p - 2; }      // p=4,5,6 -> t=2,3,4
        else if (p < 9) { g = 2; t = p - 4; }      // p=7,8   -> t=3,4
        else            { g = 3; t = 4;     }
        const int lm = l & 15, lg = l >> 4;
        const int col = t * 16 + lm;
        unsigned short v[8] = {0, 0, 0, 0, 0, 0, 0, 0};
        if (lg < 2) {
            for (int j = 0; j < 8; ++j) {
                const int krow = g * 16 + lg * 8 + j;   // feature 256+krow
                float wv = 0.f;
                if (col < DIMH)      wv = Wh[col * DT + DIMD + krow];
                else if (col < 74)   wv = Wo[(col - DIMH) * DT + DIMD + krow];
                v[j] = f2bf(wv);
            }
        }
        unsigned short* d = (unsigned short*)((char*)ws + UBOFF) + tid * 8;
        for (int j = 0; j < 8; ++j) d[j] = v[j];
    }
}

__global__ __launch_bounds__(BLOCK, 2) void caspernet_kernel(
    const float* __restrict__ x,    // [B, 256]
    const float* __restrict__ Wh,   // [64, 320]
    const float* __restrict__ bh,   // [64]
    const float* __restrict__ Wo,   // [10, 320]
    const float* __restrict__ bo,   // [10]
    const float* __restrict__ cfd,  // d_ws: [480] tri table, then B-frag blob
    float* __restrict__ out,        // [B, 10]
    int B)
{
    __shared__ short sW[80 * DIMD];     // bf16 [n][k], swizzled; 40960B
                                        //   (aliased as transpose patches in
                                        //    phase 2, after the barrier)
    __shared__ short sUB[640 * 8];      // 10 slots x 64 lanes x 8; 10240B
    __shared__ float sBias[80];         //                            320B
                                        // total ~51.5KB -> 3 blocks/CU

    const int tid = threadIdx.x;

    // ---- stage W1 = [Wh_x; Wo_x] as bf16, swizzled (short4 writes) ----
    for (int idx = tid; idx < 80 * 64; idx += BLOCK) {   // 80 rows x 64 float4
        const int n = idx >> 6, k0 = (idx & 63) * 4;
        float4 v = make_float4(0.f, 0.f, 0.f, 0.f);
        if (n < DIMH)      v = *reinterpret_cast<const float4*>(Wh + n * DT + k0);
        else if (n < 74)   v = *reinterpret_cast<const float4*>(Wo + (n - 64) * DT + k0);
        const int kz = k0 ^ ((n & 7) << 3);
        short4 sv;
        sv.x = (short)f2bf(v.x); sv.y = (short)f2bf(v.y);
        sv.z = (short)f2bf(v.z); sv.w = (short)f2bf(v.w);
        *reinterpret_cast<short4*>(sW + n * DIMD + kz) = sv;   // 8B aligned
    }
    // ---- copy prep's B-frag blob into LDS (coalesced b128) ----
    {
        const bf16x8* gUB = reinterpret_cast<const bf16x8*>((const char*)cfd + UBOFF);
        bf16x8* dUB = reinterpret_cast<bf16x8*>(sUB);
        for (int e = tid; e < 640; e += BLOCK) dUB[e] = gUB[e];
    }
    if (tid < 80) sBias[tid] = (tid < 64) ? bh[tid] : ((tid < 74) ? bo[tid - 64] : 0.f);
    __syncthreads();

    const int l  = tid & 63;
    const int w  = tid >> 6;            // wave 0..7 -> rows w*16..w*16+15
    const int lm = l & 15, lg = l >> 4;

    // ---- phase 1: one 16-row tile per wave (R9/R12 structure) ----
    const size_t rowA = (size_t)blockIdx.x * TM + w * 16 + lm;
    const float* xr = x + rowA * DIMD + lg * 8;

    f32x4 acc[NT];
    #pragma unroll
    for (int t = 0; t < NT; ++t) acc[t] = (f32x4){0.f, 0.f, 0.f, 0.f};

    #pragma unroll
    for (int ks = 0; ks < 8; ++ks) {
        const float4 xa = *reinterpret_cast<const float4*>(xr + ks * 32);
        const float4 xb = *reinterpret_cast<const float4*>(xr + ks * 32 + 4);
        bf16x8 af;
        af[0] = (short)f2bf(xa.x); af[1] = (short)f2bf(xa.y);
        af[2] = (short)f2bf(xa.z); af[3] = (short)f2bf(xa.w);
        af[4] = (short)f2bf(xb.x); af[5] = (short)f2bf(xb.y);
        af[6] = (short)f2bf(xb.z); af[7] = (short)f2bf(xb.w);
        #pragma unroll
        for (int t = 0; t < NT; ++t) {
            const int n = t * 16 + lm;
            const int kz = (lg * 8 + ks * 32) ^ ((n & 7) << 3);
            const bf16x8 bf = *reinterpret_cast<const bf16x8*>(sW + n * DIMD + kz);
            acc[t] = __builtin_amdgcn_mfma_f32_16x16x32_bf16(af, bf, acc[t], 0, 0, 0);
        }
    }
    #pragma unroll
    for (int t = 0; t < NT; ++t) {
        const float bt = sBias[t * 16 + lm];
        acc[t][0] += bt; acc[t][1] += bt; acc[t][2] += bt; acc[t][3] += bt;
    }

    __syncthreads();                    // sW dead -> alias as patches

    // ---- phase 2: blocked cascade; per-wave patch aliased into sW ----
    float* tb = reinterpret_cast<float*>(sW) + w * 320;   // 16x20 f32/wave
    #pragma unroll
    for (int g = 0; g < 4; ++g) {
        // 1) transpose tile g: C(col=lm, row=lg*4+r) -> tb[row*20+col]
        #pragma unroll
        for (int r = 0; r < 4; ++r)
            tb[(lg * 4 + r) * 20 + lm] = acc[g][r];
        // lane lm picks up its ROW (4 lg copies read same addr = broadcast)
        float s[16];
        #pragma unroll
        for (int q = 0; q < 4; ++q) {
            const f32x4 v = *reinterpret_cast<const f32x4*>(tb + lm * 20 + q * 4);
            s[q * 4 + 0] = v[0]; s[q * 4 + 1] = v[1];
            s[q * 4 + 2] = v[2]; s[q * 4 + 3] = v[3];
        }
        // 2) lane-local triangular solve, SCATTER form (bit-identical
        //    add order to R16's gather: k ascending into each s[j])
        const float* cg = cfd + g * 120;
        float h[16];
        #pragma unroll
        for (int k = 0; k < 16; ++k) {
            h[k] = sigm(s[k]);
            #pragma unroll
            for (int j = k + 1; j < 16; ++j)
                s[j] = fmaf(cg[j * (j - 1) / 2 + k], h[k], s[j]);
        }
        // 3) A-frag from local h (lg selects k-chunk; lg>=2 are K-pad zeros)
        bf16x8 haf;
        #pragma unroll
        for (int j = 0; j < 8; ++j) {
            const float hv = (lg == 0) ? h[j] : ((lg == 1) ? h[8 + j] : 0.f);
            haf[j] = (short)f2bf(hv);
        }
        // 4) rank-16 MFMA update of all future tiles (incl. head tile 4)
        const int pbase = (g == 0) ? 0 : (g == 1) ? 4 : (g == 2) ? 7 : 9;
        #pragma unroll
        for (int t = g + 1; t < NT; ++t) {
            const bf16x8 bf = *reinterpret_cast<const bf16x8*>(
                sUB + (pbase + t - g - 1) * 512 + l * 8);
            acc[t] = __builtin_amdgcn_mfma_f32_16x16x32_bf16(haf, bf, acc[t], 0, 0, 0);
        }
    }

    // ---- store head tile (cols 64..73 = C-tile 4) ----
    if (lm < DIMO) {
        const size_t orow0 = (size_t)blockIdx.x * TM + w * 16 + lg * 4;
        #pragma unroll
        for (int r = 0; r < 4; ++r)
            out[(orow0 + r) * DIMO + lm] = acc[4][r];
    }
}

extern "C" void kernel_launch(void* const* d_in, const int* in_sizes, int n_in,
                              void* d_out, int out_size, void* d_ws, size_t ws_size,
                              hipStream_t stream) {
    const float* x  = (const float*)d_in[0];
    const float* Wh = (const float*)d_in[1];
    const float* bh = (const float*)d_in[2];
    const float* Wo = (const float*)d_in[3];
    const float* bo = (const float*)d_in[4];
    float* out = (float*)d_out;
    float* ws  = (float*)d_ws;                 // 2048B tri table + 10240B UB

    const int B = in_sizes[0] / DIMD;          // 131072

    hipLaunchKernelGGL(caspernet_prep, dim3(1), dim3(640), 0, stream,
                       Wh, Wo, ws);

    const int grid = B / TM;                   // 1024
    hipLaunchKernelGGL(caspernet_kernel, dim3(grid), dim3(BLOCK), 0, stream,
                       x, Wh, bh, Wo, bo, ws, out, B);
}

// Round 18
// 50.408 us; speedup vs baseline: 1.0450x; 1.0450x over previous
//
#include <hip/hip_runtime.h>
#include <math.h>

// CasperNet R18: B=131072, D=256, H=64, O=10.
// R16=50us, R17=52.7us: TLP doesn't convert (occ stuck 40%, both pipes
// <25%) -> per-wave serial latency binds: 4x{transpose round-trip +
// 16-link sigmoid chain} + 8 dependent x-load->MFMA steps ~ 6K cy/wave.
// Fix: 2 independent 16-row tiles PER WAVE (TM=256, 8 waves x 32 rows):
// the two tiles' chains interleave in-wave (ILP), ~halving visible
// latency. Live set ~100 < 128 cap at (512,2) (R6-R8's 2-chain spills
// were at the old fat cascade; R16 structure is lean: VGPR 52 @ 1 tile).
// B-frags read once per group, shared by both tiles' MFMAs. Grid 512 =
// exactly 2 blocks/CU. Gather solve (R16 form; R17 scatter was neutral-).
// Layout (verified R5): MFMA C: col=lane&15, row=(lane>>4)*4+reg;
// A-frag: lane(lm,lg) = A[row=lm][k=lg*8+j].

#define DIMD 256
#define DIMH 64
#define DIMO 10
#define DT   320
#define NT   5        // 5 n-tiles of 16 = 80 cols (74 used)
#define TM   256      // rows per block: 8 waves x 32
#define BLOCK 512
#define UBOFF 2048    // byte offset of B-frag blob in d_ws (16B aligned)

typedef __attribute__((ext_vector_type(4))) float f32x4;
typedef __attribute__((ext_vector_type(8))) short bf16x8;

__device__ inline unsigned short f2bf(float f) {   // RNE, deterministic
    union { float f; unsigned u; } v; v.f = f;
    unsigned r = v.u + 0x7FFFu + ((v.u >> 16) & 1u);
    return (unsigned short)(r >> 16);
}
__device__ inline float sigm(float s) {
    return __builtin_amdgcn_rcpf(1.0f + __expf(-s));   // v_rcp_f32
}

// ---- prep: (a) 480-float tri table cfd[g][k(k-1)/2+m] = U diag blocks;
//            (b) 640 x u16x8 B-frag blob for the 10 (g,t) MFMA slots ----
__global__ void caspernet_prep(const float* __restrict__ Wh,
                               const float* __restrict__ Wo,
                               float* __restrict__ ws)
{
    const int tid = threadIdx.x;
    if (tid < 480) {
        const int g = tid / 120, r = tid % 120;
        int k = 1;
        while (k * (k + 1) / 2 <= r) ++k;          // k(k-1)/2 <= r < k(k+1)/2
        const int m = r - k * (k - 1) / 2;
        ws[tid] = Wh[(g * 16 + k) * DT + DIMD + (g * 16 + m)];
    }
    if (tid < 640) {
        const int p = tid >> 6, l = tid & 63;
        int g, t;
        if      (p < 4) { g = 0; t = p + 1; }
        else if (p < 7) { g = 1; t = p - 2; }      // p=4,5,6 -> t=2,3,4
        else if (p < 9) { g = 2; t = p - 4; }      // p=7,8   -> t=3,4
        else            { g = 3; t = 4;     }
        const int lm = l & 15, lg = l >> 4;
        const int col = t * 16 + lm;
        unsigned short v[8] = {0, 0, 0, 0, 0, 0, 0, 0};
        if (lg < 2) {
            for (int j = 0; j < 8; ++j) {
                const int krow = g * 16 + lg * 8 + j;   // feature 256+krow
                float wv = 0.f;
                if (col < DIMH)      wv = Wh[col * DT + DIMD + krow];
                else if (col < 74)   wv = Wo[(col - DIMH) * DT + DIMD + krow];
                v[j] = f2bf(wv);
            }
        }
        unsigned short* d = (unsigned short*)((char*)ws + UBOFF) + tid * 8;
        for (int j = 0; j < 8; ++j) d[j] = v[j];
    }
}

__global__ __launch_bounds__(BLOCK, 2) void caspernet_kernel(
    const float* __restrict__ x,    // [B, 256]
    const float* __restrict__ Wh,   // [64, 320]
    const float* __restrict__ bh,   // [64]
    const float* __restrict__ Wo,   // [10, 320]
    const float* __restrict__ bo,   // [10]
    const float* __restrict__ cfd,  // d_ws: [480] tri table, then B-frag blob
    float* __restrict__ out,        // [B, 10]
    int B)
{
    __shared__ short sW[80 * DIMD];     // bf16 [n][k], swizzled; 40960B
                                        //   (aliased as transpose patches in
                                        //    phase 2, after the barrier)
    __shared__ short sUB[640 * 8];      // 10 slots x 64 lanes x 8; 10240B
    __shared__ float sBias[80];         //                            320B
                                        // total ~51.5KB -> 2 blocks/CU

    const int tid = threadIdx.x;

    // ---- stage W1 = [Wh_x; Wo_x] as bf16, swizzled (short4 writes) ----
    for (int idx = tid; idx < 80 * 64; idx += BLOCK) {   // 80 rows x 64 float4
        const int n = idx >> 6, k0 = (idx & 63) * 4;
        float4 v = make_float4(0.f, 0.f, 0.f, 0.f);
        if (n < DIMH)      v = *reinterpret_cast<const float4*>(Wh + n * DT + k0);
        else if (n < 74)   v = *reinterpret_cast<const float4*>(Wo + (n - 64) * DT + k0);
        const int kz = k0 ^ ((n & 7) << 3);
        short4 sv;
        sv.x = (short)f2bf(v.x); sv.y = (short)f2bf(v.y);
        sv.z = (short)f2bf(v.z); sv.w = (short)f2bf(v.w);
        *reinterpret_cast<short4*>(sW + n * DIMD + kz) = sv;   // 8B aligned
    }
    // ---- copy prep's B-frag blob into LDS (coalesced b128) ----
    {
        const bf16x8* gUB = reinterpret_cast<const bf16x8*>((const char*)cfd + UBOFF);
        bf16x8* dUB = reinterpret_cast<bf16x8*>(sUB);
        for (int e = tid; e < 640; e += BLOCK) dUB[e] = gUB[e];
    }
    if (tid < 80) sBias[tid] = (tid < 64) ? bh[tid] : ((tid < 74) ? bo[tid - 64] : 0.f);
    __syncthreads();

    const int l  = tid & 63;
    const int w  = tid >> 6;            // wave 0..7 -> rows w*32 .. w*32+31
    const int lm = l & 15, lg = l >> 4;
    const size_t rowbase = (size_t)blockIdx.x * TM + w * 32;

    // ---- phase 1: two 16-row tiles per wave ----
    const float* xr0 = x + (rowbase +      lm) * DIMD + lg * 8;
    const float* xr1 = x + (rowbase + 16 + lm) * DIMD + lg * 8;

    f32x4 acc[2][NT];
    #pragma unroll
    for (int u = 0; u < 2; ++u)
        #pragma unroll
        for (int t = 0; t < NT; ++t) acc[u][t] = (f32x4){0.f, 0.f, 0.f, 0.f};

    #pragma unroll
    for (int ks = 0; ks < 8; ++ks) {
        const float4 xa0 = *reinterpret_cast<const float4*>(xr0 + ks * 32);
        const float4 xb0 = *reinterpret_cast<const float4*>(xr0 + ks * 32 + 4);
        const float4 xa1 = *reinterpret_cast<const float4*>(xr1 + ks * 32);
        const float4 xb1 = *reinterpret_cast<const float4*>(xr1 + ks * 32 + 4);
        bf16x8 af0, af1;
        af0[0] = (short)f2bf(xa0.x); af0[1] = (short)f2bf(xa0.y);
        af0[2] = (short)f2bf(xa0.z); af0[3] = (short)f2bf(xa0.w);
        af0[4] = (short)f2bf(xb0.x); af0[5] = (short)f2bf(xb0.y);
        af0[6] = (short)f2bf(xb0.z); af0[7] = (short)f2bf(xb0.w);
        af1[0] = (short)f2bf(xa1.x); af1[1] = (short)f2bf(xa1.y);
        af1[2] = (short)f2bf(xa1.z); af1[3] = (short)f2bf(xa1.w);
        af1[4] = (short)f2bf(xb1.x); af1[5] = (short)f2bf(xb1.y);
        af1[6] = (short)f2bf(xb1.z); af1[7] = (short)f2bf(xb1.w);
        #pragma unroll
        for (int t = 0; t < NT; ++t) {
            const int n = t * 16 + lm;
            const int kz = (lg * 8 + ks * 32) ^ ((n & 7) << 3);
            const bf16x8 bf = *reinterpret_cast<const bf16x8*>(sW + n * DIMD + kz);
            acc[0][t] = __builtin_amdgcn_mfma_f32_16x16x32_bf16(af0, bf, acc[0][t], 0, 0, 0);
            acc[1][t] = __builtin_amdgcn_mfma_f32_16x16x32_bf16(af1, bf, acc[1][t], 0, 0, 0);
        }
    }
    #pragma unroll
    for (int t = 0; t < NT; ++t) {
        const float bt = sBias[t * 16 + lm];
        #pragma unroll
        for (int u = 0; u < 2; ++u) {
            acc[u][t][0] += bt; acc[u][t][1] += bt;
            acc[u][t][2] += bt; acc[u][t][3] += bt;
        }
    }

    __syncthreads();                    // sW dead -> alias as patches

    // ---- phase 2: blocked cascade; two patches per wave in sW space ----
    float* tb0 = reinterpret_cast<float*>(sW) + w * 640;        // 16x20 f32
    float* tb1 = tb0 + 320;
    #pragma unroll
    for (int g = 0; g < 4; ++g) {
        // 1) transpose tile g of BOTH row-tiles
        #pragma unroll
        for (int r = 0; r < 4; ++r) {
            tb0[(lg * 4 + r) * 20 + lm] = acc[0][g][r];
            tb1[(lg * 4 + r) * 20 + lm] = acc[1][g][r];
        }
        float s0[16], s1[16];
        #pragma unroll
        for (int q = 0; q < 4; ++q) {
            const f32x4 v0 = *reinterpret_cast<const f32x4*>(tb0 + lm * 20 + q * 4);
            const f32x4 v1 = *reinterpret_cast<const f32x4*>(tb1 + lm * 20 + q * 4);
            #pragma unroll
            for (int e = 0; e < 4; ++e) { s0[q * 4 + e] = v0[e]; s1[q * 4 + e] = v1[e]; }
        }
        // 2) lane-local triangular solves (gather form; chains interleave)
        const float* cg = cfd + g * 120;
        float h0[16], h1[16];
        h0[0] = sigm(s0[0]);
        h1[0] = sigm(s1[0]);
        #pragma unroll
        for (int k = 1; k < 16; ++k) {
            float a0 = s0[k], a1 = s1[k];
            #pragma unroll
            for (int m = 0; m < k; ++m) {
                const float c = cg[k * (k - 1) / 2 + m];
                a0 = fmaf(c, h0[m], a0);
                a1 = fmaf(c, h1[m], a1);
            }
            h0[k] = sigm(a0);
            h1[k] = sigm(a1);
        }
        // 3) A-frags from local h (lg selects k-chunk; lg>=2 = K-pad zeros)
        bf16x8 haf0, haf1;
        #pragma unroll
        for (int j = 0; j < 8; ++j) {
            const float v0 = (lg == 0) ? h0[j] : ((lg == 1) ? h0[8 + j] : 0.f);
            const float v1 = (lg == 0) ? h1[j] : ((lg == 1) ? h1[8 + j] : 0.f);
            haf0[j] = (short)f2bf(v0);
            haf1[j] = (short)f2bf(v1);
        }
        // 4) rank-16 MFMA updates; B-frag shared by both tiles
        const int pbase = (g == 0) ? 0 : (g == 1) ? 4 : (g == 2) ? 7 : 9;
        #pragma unroll
        for (int t = g + 1; t < NT; ++t) {
            const bf16x8 bf = *reinterpret_cast<const bf16x8*>(
                sUB + (pbase + t - g - 1) * 512 + l * 8);
            acc[0][t] = __builtin_amdgcn_mfma_f32_16x16x32_bf16(haf0, bf, acc[0][t], 0, 0, 0);
            acc[1][t] = __builtin_amdgcn_mfma_f32_16x16x32_bf16(haf1, bf, acc[1][t], 0, 0, 0);
        }
    }

    // ---- store head tiles (cols 64..73 = C-tile 4) ----
    if (lm < DIMO) {
        #pragma unroll
        for (int u = 0; u < 2; ++u) {
            const size_t orow0 = rowbase + u * 16 + lg * 4;
            #pragma unroll
            for (int r = 0; r < 4; ++r)
                out[(orow0 + r) * DIMO + lm] = acc[u][4][r];
        }
    }
}

extern "C" void kernel_launch(void* const* d_in, const int* in_sizes, int n_in,
                              void* d_out, int out_size, void* d_ws, size_t ws_size,
                              hipStream_t stream) {
    const float* x  = (const float*)d_in[0];
    const float* Wh = (const float*)d_in[1];
    const float* bh = (const float*)d_in[2];
    const float* Wo = (const float*)d_in[3];
    const float* bo = (const float*)d_in[4];
    float* out = (float*)d_out;
    float* ws  = (float*)d_ws;                 // 2048B tri table + 10240B UB

    const int B = in_sizes[0] / DIMD;          // 131072

    hipLaunchKernelGGL(caspernet_prep, dim3(1), dim3(640), 0, stream,
                       Wh, Wo, ws);

    const int grid = B / TM;                   // 512 = 2 blocks/CU x 256 CUs
    hipLaunchKernelGGL(caspernet_kernel, dim3(grid), dim3(BLOCK), 0, stream,
                       x, Wh, bh, Wo, bo, ws, out, B);
}

// Round 19
// 47.527 us; speedup vs baseline: 1.1083x; 1.0606x over previous
//
#include <hip/hip_runtime.h>
#include <math.h>

// CasperNet R19: B=131072, D=256, H=64, O=10.
// R16/R17/R18 (three structures) all pin at 50+-2.5us with NOTHING
// saturated (VALU 22%, MFMA 3%, occ 44%, HBM 12%) -> suspect the
// prep->main two-kernel graph (node overhead + serialized d_ws warm-up).
// R19 fuses everything into ONE kernel, bit-identical math:
//  - tri table: solve s_loads DIRECTLY from Wh (wave-uniform addrs,
//    ~4KB of diagonal blocks -> scalar-cache; compiler hoists the
//    s_load chains so warm-up overlaps phase-1).
//  - B-frag blob: built in-block from Wh/Wo (contiguous 32B per entry,
//    10KB/block, L2-warm) instead of prep-written d_ws.
// Structure = R16 single-tile gather solve + R17 LDS aliasing (51.5KB),
// TM=128, BLOCK=512, grid=1024, (512,2) cap.
// Layout (verified R5): MFMA C: col=lane&15, row=(lane>>4)*4+reg;
// A-frag: lane(lm,lg) = A[row=lm][k=lg*8+j].

#define DIMD 256
#define DIMH 64
#define DIMO 10
#define DT   320
#define NT   5        // 5 n-tiles of 16 = 80 cols (74 used)
#define TM   128      // rows per block: 8 waves x 16
#define BLOCK 512

typedef __attribute__((ext_vector_type(4))) float f32x4;
typedef __attribute__((ext_vector_type(8))) short bf16x8;

__device__ inline unsigned short f2bf(float f) {   // RNE, deterministic
    union { float f; unsigned u; } v; v.f = f;
    unsigned r = v.u + 0x7FFFu + ((v.u >> 16) & 1u);
    return (unsigned short)(r >> 16);
}
__device__ inline float sigm(float s) {
    return __builtin_amdgcn_rcpf(1.0f + __expf(-s));   // v_rcp_f32
}

__global__ __launch_bounds__(BLOCK, 2) void caspernet_kernel(
    const float* __restrict__ x,    // [B, 256]
    const float* __restrict__ Wh,   // [64, 320]
    const float* __restrict__ bh,   // [64]
    const float* __restrict__ Wo,   // [10, 320]
    const float* __restrict__ bo,   // [10]
    float* __restrict__ out,        // [B, 10]
    int B)
{
    __shared__ short sW[80 * DIMD];     // bf16 [n][k], swizzled; 40960B
                                        //   (aliased as transpose patches in
                                        //    phase 2, after the barrier)
    __shared__ short sUB[640 * 8];      // 10 slots x 64 lanes x 8; 10240B
    __shared__ float sBias[80];         //                            320B
                                        // total ~51.5KB -> 2-3 blocks/CU

    const int tid = threadIdx.x;

    // ---- stage W1 = [Wh_x; Wo_x] as bf16, swizzled (short4 writes) ----
    for (int idx = tid; idx < 80 * 64; idx += BLOCK) {   // 80 rows x 64 float4
        const int n = idx >> 6, k0 = (idx & 63) * 4;
        float4 v = make_float4(0.f, 0.f, 0.f, 0.f);
        if (n < DIMH)      v = *reinterpret_cast<const float4*>(Wh + n * DT + k0);
        else if (n < 74)   v = *reinterpret_cast<const float4*>(Wo + (n - 64) * DT + k0);
        const int kz = k0 ^ ((n & 7) << 3);
        short4 sv;
        sv.x = (short)f2bf(v.x); sv.y = (short)f2bf(v.y);
        sv.z = (short)f2bf(v.z); sv.w = (short)f2bf(v.w);
        *reinterpret_cast<short4*>(sW + n * DIMD + kz) = sv;   // 8B aligned
    }
    // ---- build B-frag blob in-block (was prep-written d_ws) ----
    // slot p -> (g,t); lane l2: lm2 = col-in-tile, lg2 = k-chunk.
    // entry = 8 contiguous features 256+g*16+lg2*8.. of W row col.
    for (int e = tid; e < 640; e += BLOCK) {
        const int p = e >> 6, l2 = e & 63;
        int g, t;
        if      (p < 4) { g = 0; t = p + 1; }
        else if (p < 7) { g = 1; t = p - 2; }      // p=4,5,6 -> t=2,3,4
        else if (p < 9) { g = 2; t = p - 4; }      // p=7,8   -> t=3,4
        else            { g = 3; t = 4;     }
        const int lm2 = l2 & 15, lg2 = l2 >> 4;
        const int col = t * 16 + lm2;
        short4 lo = {0, 0, 0, 0}, hi = {0, 0, 0, 0};
        if (lg2 < 2 && col < 74) {
            const float* src = (col < DIMH)
                ? (Wh + col * DT + DIMD + g * 16 + lg2 * 8)
                : (Wo + (col - DIMH) * DT + DIMD + g * 16 + lg2 * 8);
            const float4 a = *reinterpret_cast<const float4*>(src);
            const float4 b = *reinterpret_cast<const float4*>(src + 4);
            lo.x = (short)f2bf(a.x); lo.y = (short)f2bf(a.y);
            lo.z = (short)f2bf(a.z); lo.w = (short)f2bf(a.w);
            hi.x = (short)f2bf(b.x); hi.y = (short)f2bf(b.y);
            hi.z = (short)f2bf(b.z); hi.w = (short)f2bf(b.w);
        }
        *reinterpret_cast<short4*>(sUB + e * 8)     = lo;
        *reinterpret_cast<short4*>(sUB + e * 8 + 4) = hi;
    }
    if (tid < 80) sBias[tid] = (tid < 64) ? bh[tid] : ((tid < 74) ? bo[tid - 64] : 0.f);
    __syncthreads();

    const int l  = tid & 63;
    const int w  = tid >> 6;            // wave 0..7 -> rows w*16..w*16+15
    const int lm = l & 15, lg = l >> 4;

    // ---- phase 1: one 16-row tile per wave ----
    const size_t rowA = (size_t)blockIdx.x * TM + w * 16 + lm;
    const float* xr = x + rowA * DIMD + lg * 8;

    f32x4 acc[NT];
    #pragma unroll
    for (int t = 0; t < NT; ++t) acc[t] = (f32x4){0.f, 0.f, 0.f, 0.f};

    #pragma unroll
    for (int ks = 0; ks < 8; ++ks) {
        const float4 xa = *reinterpret_cast<const float4*>(xr + ks * 32);
        const float4 xb = *reinterpret_cast<const float4*>(xr + ks * 32 + 4);
        bf16x8 af;
        af[0] = (short)f2bf(xa.x); af[1] = (short)f2bf(xa.y);
        af[2] = (short)f2bf(xa.z); af[3] = (short)f2bf(xa.w);
        af[4] = (short)f2bf(xb.x); af[5] = (short)f2bf(xb.y);
        af[6] = (short)f2bf(xb.z); af[7] = (short)f2bf(xb.w);
        #pragma unroll
        for (int t = 0; t < NT; ++t) {
            const int n = t * 16 + lm;
            const int kz = (lg * 8 + ks * 32) ^ ((n & 7) << 3);
            const bf16x8 bf = *reinterpret_cast<const bf16x8*>(sW + n * DIMD + kz);
            acc[t] = __builtin_amdgcn_mfma_f32_16x16x32_bf16(af, bf, acc[t], 0, 0, 0);
        }
    }
    #pragma unroll
    for (int t = 0; t < NT; ++t) {
        const float bt = sBias[t * 16 + lm];
        acc[t][0] += bt; acc[t][1] += bt; acc[t][2] += bt; acc[t][3] += bt;
    }

    __syncthreads();                    // sW dead -> alias as patches

    // ---- phase 2: blocked cascade; per-wave patch aliased into sW ----
    float* tb = reinterpret_cast<float*>(sW) + w * 320;   // 16x20 f32/wave
    #pragma unroll
    for (int g = 0; g < 4; ++g) {
        // 1) transpose tile g: C(col=lm, row=lg*4+r) -> tb[row*20+col]
        #pragma unroll
        for (int r = 0; r < 4; ++r)
            tb[(lg * 4 + r) * 20 + lm] = acc[g][r];
        // lane lm picks up its ROW (4 lg copies read same addr = broadcast)
        float s[16];
        #pragma unroll
        for (int q = 0; q < 4; ++q) {
            const f32x4 v = *reinterpret_cast<const f32x4*>(tb + lm * 20 + q * 4);
            s[q * 4 + 0] = v[0]; s[q * 4 + 1] = v[1];
            s[q * 4 + 2] = v[2]; s[q * 4 + 3] = v[3];
        }
        // 2) lane-local triangular solve (gather form); coefficients are
        //    wave-uniform s_loads DIRECTLY from Wh (same f32 values the
        //    prep table held -> bit-identical)
        const float* cg = Wh + (g * 16) * DT + DIMD + g * 16;  // c(k,m)=cg[k*DT+m]
        float h[16];
        h[0] = sigm(s[0]);
        #pragma unroll
        for (int k = 1; k < 16; ++k) {
            float a_ = s[k];
            #pragma unroll
            for (int m = 0; m < k; ++m)
                a_ = fmaf(cg[k * DT + m], h[m], a_);
            h[k] = sigm(a_);
        }
        // 3) A-frag from local h (lg selects k-chunk; lg>=2 are K-pad zeros)
        bf16x8 haf;
        #pragma unroll
        for (int j = 0; j < 8; ++j) {
            const float hv = (lg == 0) ? h[j] : ((lg == 1) ? h[8 + j] : 0.f);
            haf[j] = (short)f2bf(hv);
        }
        // 4) rank-16 MFMA update of all future tiles (incl. head tile 4)
        const int pbase = (g == 0) ? 0 : (g == 1) ? 4 : (g == 2) ? 7 : 9;
        #pragma unroll
        for (int t = g + 1; t < NT; ++t) {
            const bf16x8 bf = *reinterpret_cast<const bf16x8*>(
                sUB + (pbase + t - g - 1) * 512 + l * 8);
            acc[t] = __builtin_amdgcn_mfma_f32_16x16x32_bf16(haf, bf, acc[t], 0, 0, 0);
        }
    }

    // ---- store head tile (cols 64..73 = C-tile 4) ----
    if (lm < DIMO) {
        const size_t orow0 = (size_t)blockIdx.x * TM + w * 16 + lg * 4;
        #pragma unroll
        for (int r = 0; r < 4; ++r)
            out[(orow0 + r) * DIMO + lm] = acc[4][r];
    }
}

extern "C" void kernel_launch(void* const* d_in, const int* in_sizes, int n_in,
                              void* d_out, int out_size, void* d_ws, size_t ws_size,
                              hipStream_t stream) {
    const float* x  = (const float*)d_in[0];
    const float* Wh = (const float*)d_in[1];
    const float* bh = (const float*)d_in[2];
    const float* Wo = (const float*)d_in[3];
    const float* bo = (const float*)d_in[4];
    float* out = (float*)d_out;

    const int B = in_sizes[0] / DIMD;      // 131072
    const int grid = B / TM;               // 1024

    hipLaunchKernelGGL(caspernet_kernel, dim3(grid), dim3(BLOCK), 0, stream,
                       x, Wh, bh, Wo, bo, out, B);
}

// Round 20
// 46.836 us; speedup vs baseline: 1.1247x; 1.0148x over previous
//
#include <hip/hip_runtime.h>
#include <math.h>

// CasperNet R20: B=131072, D=256, H=64, O=10.
// vs R19 (47.5us, VGPR=40, VALU 22%, all pipes idle -> latency-bound):
// the compiler's minimal 40-reg allocation strangles phase-1's load
// window (16 dependent float4 x loads, ~2 in flight -> ~8 serial L2/L3
// latencies per wave). Fix: EXPLICIT FULL PREFETCH -- all 16 x loads
// issued back-to-back into statically-indexed xv[16] (64 VGPRs) before
// any cvt/MFMA -> one memory latency. Live ~104 < 128 cap at (512,2).
// Residency 3->2 blocks/CU (VGPR>85), acceptable: R12/R19 showed waves
// convert weakly; this cuts ~4K cy off each wave's critical path.
// Math byte-identical to R19 (same ops, same order).
// Layout (verified R5): MFMA C: col=lane&15, row=(lane>>4)*4+reg;
// A-frag: lane(lm,lg) = A[row=lm][k=lg*8+j].

#define DIMD 256
#define DIMH 64
#define DIMO 10
#define DT   320
#define NT   5        // 5 n-tiles of 16 = 80 cols (74 used)
#define TM   128      // rows per block: 8 waves x 16
#define BLOCK 512

typedef __attribute__((ext_vector_type(4))) float f32x4;
typedef __attribute__((ext_vector_type(8))) short bf16x8;

__device__ inline unsigned short f2bf(float f) {   // RNE, deterministic
    union { float f; unsigned u; } v; v.f = f;
    unsigned r = v.u + 0x7FFFu + ((v.u >> 16) & 1u);
    return (unsigned short)(r >> 16);
}
__device__ inline float sigm(float s) {
    return __builtin_amdgcn_rcpf(1.0f + __expf(-s));   // v_rcp_f32
}

__global__ __launch_bounds__(BLOCK, 2) void caspernet_kernel(
    const float* __restrict__ x,    // [B, 256]
    const float* __restrict__ Wh,   // [64, 320]
    const float* __restrict__ bh,   // [64]
    const float* __restrict__ Wo,   // [10, 320]
    const float* __restrict__ bo,   // [10]
    float* __restrict__ out,        // [B, 10]
    int B)
{
    __shared__ short sW[80 * DIMD];     // bf16 [n][k], swizzled; 40960B
                                        //   (aliased as transpose patches in
                                        //    phase 2, after the barrier)
    __shared__ short sUB[640 * 8];      // 10 slots x 64 lanes x 8; 10240B
    __shared__ float sBias[80];         //                            320B
                                        // total ~51.5KB

    const int tid = threadIdx.x;

    // ---- stage W1 = [Wh_x; Wo_x] as bf16, swizzled (short4 writes) ----
    for (int idx = tid; idx < 80 * 64; idx += BLOCK) {   // 80 rows x 64 float4
        const int n = idx >> 6, k0 = (idx & 63) * 4;
        float4 v = make_float4(0.f, 0.f, 0.f, 0.f);
        if (n < DIMH)      v = *reinterpret_cast<const float4*>(Wh + n * DT + k0);
        else if (n < 74)   v = *reinterpret_cast<const float4*>(Wo + (n - 64) * DT + k0);
        const int kz = k0 ^ ((n & 7) << 3);
        short4 sv;
        sv.x = (short)f2bf(v.x); sv.y = (short)f2bf(v.y);
        sv.z = (short)f2bf(v.z); sv.w = (short)f2bf(v.w);
        *reinterpret_cast<short4*>(sW + n * DIMD + kz) = sv;   // 8B aligned
    }
    // ---- build B-frag blob in-block ----
    for (int e = tid; e < 640; e += BLOCK) {
        const int p = e >> 6, l2 = e & 63;
        int g, t;
        if      (p < 4) { g = 0; t = p + 1; }
        else if (p < 7) { g = 1; t = p - 2; }      // p=4,5,6 -> t=2,3,4
        else if (p < 9) { g = 2; t = p - 4; }      // p=7,8   -> t=3,4
        else            { g = 3; t = 4;     }
        const int lm2 = l2 & 15, lg2 = l2 >> 4;
        const int col = t * 16 + lm2;
        short4 lo = {0, 0, 0, 0}, hi = {0, 0, 0, 0};
        if (lg2 < 2 && col < 74) {
            const float* src = (col < DIMH)
                ? (Wh + col * DT + DIMD + g * 16 + lg2 * 8)
                : (Wo + (col - DIMH) * DT + DIMD + g * 16 + lg2 * 8);
            const float4 a = *reinterpret_cast<const float4*>(src);
            const float4 b = *reinterpret_cast<const float4*>(src + 4);
            lo.x = (short)f2bf(a.x); lo.y = (short)f2bf(a.y);
            lo.z = (short)f2bf(a.z); lo.w = (short)f2bf(a.w);
            hi.x = (short)f2bf(b.x); hi.y = (short)f2bf(b.y);
            hi.z = (short)f2bf(b.z); hi.w = (short)f2bf(b.w);
        }
        *reinterpret_cast<short4*>(sUB + e * 8)     = lo;
        *reinterpret_cast<short4*>(sUB + e * 8 + 4) = hi;
    }
    if (tid < 80) sBias[tid] = (tid < 64) ? bh[tid] : ((tid < 74) ? bo[tid - 64] : 0.f);

    const int l  = tid & 63;
    const int w  = tid >> 6;            // wave 0..7 -> rows w*16..w*16+15
    const int lm = l & 15, lg = l >> 4;

    // ---- phase 1 prefetch: ALL 16 x float4 loads in flight at once ----
    const size_t rowA = (size_t)blockIdx.x * TM + w * 16 + lm;
    const float* xr = x + rowA * DIMD + lg * 8;

    float4 xv[16];                      // 64 VGPRs, statically indexed
    #pragma unroll
    for (int ks = 0; ks < 8; ++ks) {
        xv[2 * ks]     = *reinterpret_cast<const float4*>(xr + ks * 32);
        xv[2 * ks + 1] = *reinterpret_cast<const float4*>(xr + ks * 32 + 4);
    }

    __syncthreads();                    // staging visible

    f32x4 acc[NT];
    #pragma unroll
    for (int t = 0; t < NT; ++t) acc[t] = (f32x4){0.f, 0.f, 0.f, 0.f};

    #pragma unroll
    for (int ks = 0; ks < 8; ++ks) {
        const float4 xa = xv[2 * ks];
        const float4 xb = xv[2 * ks + 1];
        bf16x8 af;
        af[0] = (short)f2bf(xa.x); af[1] = (short)f2bf(xa.y);
        af[2] = (short)f2bf(xa.z); af[3] = (short)f2bf(xa.w);
        af[4] = (short)f2bf(xb.x); af[5] = (short)f2bf(xb.y);
        af[6] = (short)f2bf(xb.z); af[7] = (short)f2bf(xb.w);
        #pragma unroll
        for (int t = 0; t < NT; ++t) {
            const int n = t * 16 + lm;
            const int kz = (lg * 8 + ks * 32) ^ ((n & 7) << 3);
            const bf16x8 bf = *reinterpret_cast<const bf16x8*>(sW + n * DIMD + kz);
            acc[t] = __builtin_amdgcn_mfma_f32_16x16x32_bf16(af, bf, acc[t], 0, 0, 0);
        }
    }
    #pragma unroll
    for (int t = 0; t < NT; ++t) {
        const float bt = sBias[t * 16 + lm];
        acc[t][0] += bt; acc[t][1] += bt; acc[t][2] += bt; acc[t][3] += bt;
    }

    __syncthreads();                    // sW dead -> alias as patches

    // ---- phase 2: blocked cascade; per-wave patch aliased into sW ----
    float* tb = reinterpret_cast<float*>(sW) + w * 320;   // 16x20 f32/wave
    #pragma unroll
    for (int g = 0; g < 4; ++g) {
        // 1) transpose tile g: C(col=lm, row=lg*4+r) -> tb[row*20+col]
        #pragma unroll
        for (int r = 0; r < 4; ++r)
            tb[(lg * 4 + r) * 20 + lm] = acc[g][r];
        // lane lm picks up its ROW (4 lg copies read same addr = broadcast)
        float s[16];
        #pragma unroll
        for (int q = 0; q < 4; ++q) {
            const f32x4 v = *reinterpret_cast<const f32x4*>(tb + lm * 20 + q * 4);
            s[q * 4 + 0] = v[0]; s[q * 4 + 1] = v[1];
            s[q * 4 + 2] = v[2]; s[q * 4 + 3] = v[3];
        }
        // 2) lane-local triangular solve; coefficients via wave-uniform
        //    s_loads directly from Wh
        const float* cg = Wh + (g * 16) * DT + DIMD + g * 16;  // c(k,m)=cg[k*DT+m]
        float h[16];
        h[0] = sigm(s[0]);
        #pragma unroll
        for (int k = 1; k < 16; ++k) {
            float a_ = s[k];
            #pragma unroll
            for (int m = 0; m < k; ++m)
                a_ = fmaf(cg[k * DT + m], h[m], a_);
            h[k] = sigm(a_);
        }
        // 3) A-frag from local h (lg selects k-chunk; lg>=2 are K-pad zeros)
        bf16x8 haf;
        #pragma unroll
        for (int j = 0; j < 8; ++j) {
            const float hv = (lg == 0) ? h[j] : ((lg == 1) ? h[8 + j] : 0.f);
            haf[j] = (short)f2bf(hv);
        }
        // 4) rank-16 MFMA update of all future tiles (incl. head tile 4)
        const int pbase = (g == 0) ? 0 : (g == 1) ? 4 : (g == 2) ? 7 : 9;
        #pragma unroll
        for (int t = g + 1; t < NT; ++t) {
            const bf16x8 bf = *reinterpret_cast<const bf16x8*>(
                sUB + (pbase + t - g - 1) * 512 + l * 8);
            acc[t] = __builtin_amdgcn_mfma_f32_16x16x32_bf16(haf, bf, acc[t], 0, 0, 0);
        }
    }

    // ---- store head tile (cols 64..73 = C-tile 4) ----
    if (lm < DIMO) {
        const size_t orow0 = (size_t)blockIdx.x * TM + w * 16 + lg * 4;
        #pragma unroll
        for (int r = 0; r < 4; ++r)
            out[(orow0 + r) * DIMO + lm] = acc[4][r];
    }
}

extern "C" void kernel_launch(void* const* d_in, const int* in_sizes, int n_in,
                              void* d_out, int out_size, void* d_ws, size_t ws_size,
                              hipStream_t stream) {
    const float* x  = (const float*)d_in[0];
    const float* Wh = (const float*)d_in[1];
    const float* bh = (const float*)d_in[2];
    const float* Wo = (const float*)d_in[3];
    const float* bo = (const float*)d_in[4];
    float* out = (float*)d_out;

    const int B = in_sizes[0] / DIMD;      // 131072
    const int grid = B / TM;               // 1024

    hipLaunchKernelGGL(caspernet_kernel, dim3(grid), dim3(BLOCK), 0, stream,
                       x, Wh, bh, Wo, bo, out, B);
}